// Round 1
// baseline (283.466 us; speedup 1.0000x reference)
//
#include <hip/hip_runtime.h>

// CapsuleLayer dynamic routing, MI355X.
// B=32, I=2048, Ain(K)=16, D=32, A=16, O=D*A=512, num_routing=3.
//
// Forward math (stop_gradient is a no-op in forward):
//   V[b,i,o] = sum_k x[b,i,k] * W[i,k,o]
//   iter0: route uniform 1/32 -> preact0 = (1/32) * sum_i V + bias -> act0 = squash
//   iter1: l1[b,i,d] = sum_a V*act0 ; route1 = softmax_D(l1)
//          preact1 = sum_i route1*V + bias -> act1
//   iter2: l2 = l1 + sum_a V*act1 ; route2 = softmax_D(l2)
//          preact2 = sum_i route2*V + bias -> act2 = OUTPUT
//
// V is never materialized: each sweep recomputes it from x and W (537M FMA
// per pass ~7us VALU, vs 134MB votes traffic). l1 is recomputed in pass 2
// from act0, so no logits array exists either.
//
// Lane layout: within a wave, lane l owns outputs o = l + 64*j (j=0..7),
// so d = (l>>4) + 4*j, a = l&15. The softmax-over-D reduction becomes:
//   - sum over a: butterfly xor {1,2,4,8} (16-lane groups)
//   - max/sum over the 4 d-groups: butterfly xor {16,32}
// and the route value for the lane's j-th output IS its j-th softmax value.

#define B_  32
#define I_  2048
#define K_  16
#define O_  512
#define NW_ 256   // sweep workgroups
#define IC_ 8     // i's per workgroup = I_/NW_

template<int PASS>
__global__ __launch_bounds__(512)
void sweep_kernel(const float* __restrict__ x, const float* __restrict__ W,
                  const float* __restrict__ act0_g, const float* __restrict__ act1_g,
                  float* __restrict__ partial)
{
    const int tid  = threadIdx.x;
    const int lane = tid & 63;
    const int wave = tid >> 6;          // 0..7, handles b = wave*4 .. wave*4+3
    const int wg   = blockIdx.x;

    __shared__ float sW[K_ * O_];       // 32 KB: W[i] tile
    __shared__ float sX[B_ * K_];       // 2 KB: x[:, i, :]

    float facc[4][8];
    #pragma unroll
    for (int bb = 0; bb < 4; ++bb)
        #pragma unroll
        for (int j = 0; j < 8; ++j) facc[bb][j] = 0.f;

    float a0[4][8], a1[4][8];
    if (PASS >= 1) {
        #pragma unroll
        for (int bb = 0; bb < 4; ++bb) {
            const int b = wave * 4 + bb;
            #pragma unroll
            for (int j = 0; j < 8; ++j)
                a0[bb][j] = act0_g[b * O_ + lane + 64 * j];
        }
    }
    if (PASS == 2) {
        #pragma unroll
        for (int bb = 0; bb < 4; ++bb) {
            const int b = wave * 4 + bb;
            #pragma unroll
            for (int j = 0; j < 8; ++j)
                a1[bb][j] = act1_g[b * O_ + lane + 64 * j];
        }
    }

    for (int ii = 0; ii < IC_; ++ii) {
        const int i = wg * IC_ + ii;
        __syncthreads();   // protect prior iteration's LDS reads
        // stage W[i] (8192 floats) with 512 threads x 4 float4
        {
            const float4* Wg  = (const float4*)(W + (size_t)i * (K_ * O_));
            float4*       sW4 = (float4*)sW;
            #pragma unroll
            for (int q = 0; q < 4; ++q) sW4[tid + 512 * q] = Wg[tid + 512 * q];
        }
        // stage x[:, i, :] (512 floats)
        sX[tid] = x[((size_t)(tid >> 4) * I_ + i) * K_ + (tid & 15)];
        __syncthreads();

        // recompute V[b, o=lane+64j] for this wave's 4 b's
        float V[4][8];
        #pragma unroll
        for (int bb = 0; bb < 4; ++bb)
            #pragma unroll
            for (int j = 0; j < 8; ++j) V[bb][j] = 0.f;
        #pragma unroll
        for (int k = 0; k < K_; ++k) {
            float w[8];
            #pragma unroll
            for (int j = 0; j < 8; ++j) w[j] = sW[k * O_ + lane + 64 * j];
            #pragma unroll
            for (int bb = 0; bb < 4; ++bb) {
                const float xb = sX[(wave * 4 + bb) * K_ + k];
                #pragma unroll
                for (int j = 0; j < 8; ++j) V[bb][j] = fmaf(xb, w[j], V[bb][j]);
            }
        }

        #pragma unroll
        for (int bb = 0; bb < 4; ++bb) {
            if (PASS == 0) {
                #pragma unroll
                for (int j = 0; j < 8; ++j) facc[bb][j] += V[bb][j];
            } else {
                // l1 partial: one a-term per lane; reduce over a (low 4 lane bits)
                float p0[8];
                #pragma unroll
                for (int j = 0; j < 8; ++j) p0[j] = V[bb][j] * a0[bb][j];
                #pragma unroll
                for (int j = 0; j < 8; ++j) {
                    p0[j] += __shfl_xor(p0[j], 1);
                    p0[j] += __shfl_xor(p0[j], 2);
                    p0[j] += __shfl_xor(p0[j], 4);
                    p0[j] += __shfl_xor(p0[j], 8);
                }
                float lg[8];
                if (PASS == 1) {
                    #pragma unroll
                    for (int j = 0; j < 8; ++j) lg[j] = p0[j];
                } else {
                    float p1[8];
                    #pragma unroll
                    for (int j = 0; j < 8; ++j) p1[j] = V[bb][j] * a1[bb][j];
                    #pragma unroll
                    for (int j = 0; j < 8; ++j) {
                        p1[j] += __shfl_xor(p1[j], 1);
                        p1[j] += __shfl_xor(p1[j], 2);
                        p1[j] += __shfl_xor(p1[j], 4);
                        p1[j] += __shfl_xor(p1[j], 8);
                    }
                    #pragma unroll
                    for (int j = 0; j < 8; ++j) lg[j] = p0[j] + p1[j];
                }
                // softmax over all 32 d's (lane group g holds d = g+4j)
                float mx = lg[0];
                #pragma unroll
                for (int j = 1; j < 8; ++j) mx = fmaxf(mx, lg[j]);
                mx = fmaxf(mx, __shfl_xor(mx, 16));
                mx = fmaxf(mx, __shfl_xor(mx, 32));
                float e[8], s = 0.f;
                #pragma unroll
                for (int j = 0; j < 8; ++j) { e[j] = __expf(lg[j] - mx); s += e[j]; }
                s += __shfl_xor(s, 16);
                s += __shfl_xor(s, 32);
                const float inv = 1.f / s;
                #pragma unroll
                for (int j = 0; j < 8; ++j)
                    facc[bb][j] = fmaf(e[j] * inv, V[bb][j], facc[bb][j]);
            }
        }
    }

    // flush per-wg partial sums (each (b,o) owned by exactly one lane/j)
    #pragma unroll
    for (int bb = 0; bb < 4; ++bb) {
        const int b = wave * 4 + bb;
        float* dst = partial + ((size_t)wg * B_ + b) * O_ + lane;
        #pragma unroll
        for (int j = 0; j < 8; ++j) dst[64 * j] = facc[bb][j];
    }
}

// sum NW_ partials -> *scale + bias -> squash over A (16 consecutive o's) -> out
__global__ __launch_bounds__(256)
void reduce_squash(const float* __restrict__ partial, const float* __restrict__ bias,
                   float scale, float* __restrict__ out)
{
    const int g = blockIdx.x * 256 + threadIdx.x;   // 0..16383 = b*512 + o
    const int o = g & (O_ - 1);
    float s = 0.f;
    #pragma unroll 8
    for (int w = 0; w < NW_; ++w) s += partial[(size_t)w * (B_ * O_) + g];
    const float p = fmaf(s, scale, bias[o]);
    float nn = p * p;
    nn += __shfl_xor(nn, 1);
    nn += __shfl_xor(nn, 2);
    nn += __shfl_xor(nn, 4);
    nn += __shfl_xor(nn, 8);
    out[g] = p * sqrtf(nn) / (1.f + nn);
}

extern "C" void kernel_launch(void* const* d_in, const int* in_sizes, int n_in,
                              void* d_out, int out_size, void* d_ws, size_t ws_size,
                              hipStream_t stream) {
    const float* x    = (const float*)d_in[0];   // [32,2048,16]
    const float* W    = (const float*)d_in[1];   // [2048,16,512]
    const float* bias = (const float*)d_in[2];   // [512]
    // d_in[3] = num_routing (fixed at 3; loop structure hardcoded)
    float* out = (float*)d_out;                  // [32,512] f32

    float* partial = (float*)d_ws;                       // NW_*32*512 f32 = 16.8 MB
    float* act0    = partial + (size_t)NW_ * B_ * O_;    // 64 KB
    float* act1    = act0 + B_ * O_;                     // 64 KB

    sweep_kernel<0><<<NW_, 512, 0, stream>>>(x, W, nullptr, nullptr, partial);
    reduce_squash<<<64, 256, 0, stream>>>(partial, bias, 1.f / 32.f, act0);
    sweep_kernel<1><<<NW_, 512, 0, stream>>>(x, W, act0, nullptr, partial);
    reduce_squash<<<64, 256, 0, stream>>>(partial, bias, 1.f, act1);
    sweep_kernel<2><<<NW_, 512, 0, stream>>>(x, W, act0, act1, partial);
    reduce_squash<<<64, 256, 0, stream>>>(partial, bias, 1.f, out);
}

// Round 2
// 225.458 us; speedup vs baseline: 1.2573x; 1.2573x over previous
//
#include <hip/hip_runtime.h>

// CapsuleLayer dynamic routing, MI355X. R1: transposed lane layout + 2x grid.
// B=32, I=2048, K=16, O=D*A=512 (D=32, A=16), num_routing=3.
//
// Lane layout (sweep): lane l owns d = l&31, h = l>>5, outputs
// o = d*16 + h*8 + j (j=0..7). Routing reductions:
//   - sum over a: 8-term in-register dot + one shfl_xor(32)
//   - softmax over D: xor{1,2,4,8,16} butterfly (lanes 0..31 / dup in 32..63)
// W staged into LDS permuted: sW[k*512 + j*64 + (h*32+d)] so the hot-loop
// read sW[k*512 + j*64 + lane] is lane-contiguous (conflict-free).
//
// Grid: 512 wgs x 256 thr = (256 i-groups) x (2 batch halves); each wave
// handles 4 b's of its half; 8 i's per wg. 2-4 wgs/CU co-resident (vs 1
// before) to overlap staging latency with compute.

#define B_  32
#define I_  2048
#define K_  16
#define O_  512
#define NG_ 256   // i-groups (partial-buffer leading dim)
#define IC_ 8     // i's per group

template<int PASS>
__global__ __launch_bounds__(256)
void sweep_kernel(const float* __restrict__ x, const float* __restrict__ W,
                  const float* __restrict__ act0_g, const float* __restrict__ act1_g,
                  float* __restrict__ partial)
{
    const int tid  = threadIdx.x;
    const int lane = tid & 63;
    const int wave = tid >> 6;              // 0..3
    const int ig   = blockIdx.x >> 1;       // i-group
    const int bh   = blockIdx.x & 1;        // batch half
    const int d    = lane & 31;
    const int h    = lane >> 5;
    const int obase = d * 16 + h * 8;       // lane's first o

    __shared__ float sW[K_ * O_];           // 32 KB, permuted W[i] tile
    __shared__ float sX[16 * K_];           // 1 KB: x[b-half, i, :]

    float facc[4][8];
    #pragma unroll
    for (int bb = 0; bb < 4; ++bb)
        #pragma unroll
        for (int j = 0; j < 8; ++j) facc[bb][j] = 0.f;

    float a0[4][8], a1[4][8];
    if (PASS >= 1) {
        #pragma unroll
        for (int bb = 0; bb < 4; ++bb) {
            const int b = bh * 16 + wave * 4 + bb;
            const float4* p = (const float4*)(act0_g + b * O_ + obase);
            float4 f0 = p[0], f1 = p[1];
            a0[bb][0]=f0.x; a0[bb][1]=f0.y; a0[bb][2]=f0.z; a0[bb][3]=f0.w;
            a0[bb][4]=f1.x; a0[bb][5]=f1.y; a0[bb][6]=f1.z; a0[bb][7]=f1.w;
        }
    }
    if (PASS == 2) {
        #pragma unroll
        for (int bb = 0; bb < 4; ++bb) {
            const int b = bh * 16 + wave * 4 + bb;
            const float4* p = (const float4*)(act1_g + b * O_ + obase);
            float4 f0 = p[0], f1 = p[1];
            a1[bb][0]=f0.x; a1[bb][1]=f0.y; a1[bb][2]=f0.z; a1[bb][3]=f0.w;
            a1[bb][4]=f1.x; a1[bb][5]=f1.y; a1[bb][6]=f1.z; a1[bb][7]=f1.w;
        }
    }

    for (int ii = 0; ii < IC_; ++ii) {
        const int i = ig * IC_ + ii;
        __syncthreads();   // protect prior iteration's LDS reads
        // stage W[i] permuted: 2048 float4s, 8 per thread
        {
            const float4* Wg = (const float4*)(W + (size_t)i * (K_ * O_));
            #pragma unroll
            for (int q = 0; q < 8; ++q) {
                const int f = tid + 256 * q;
                float4 w4 = Wg[f];
                const int flat = 4 * f;
                const int k  = flat >> 9;
                const int o  = flat & (O_ - 1);
                const int dd = o >> 4;
                const int aa = o & 15;
                const int hh = aa >> 3;
                const int j0 = aa & 7;           // 0 or 4
                const int base = k * O_ + hh * 32 + dd;
                sW[base + (j0 + 0) * 64] = w4.x;
                sW[base + (j0 + 1) * 64] = w4.y;
                sW[base + (j0 + 2) * 64] = w4.z;
                sW[base + (j0 + 3) * 64] = w4.w;
            }
        }
        // stage x for this half's 16 b's
        sX[tid & 255] = x[((size_t)(bh * 16 + (tid >> 4)) * I_ + i) * K_ + (tid & 15)];
        __syncthreads();

        // V[bb][j] for this wave's 4 b's
        float V[4][8];
        #pragma unroll
        for (int bb = 0; bb < 4; ++bb)
            #pragma unroll
            for (int j = 0; j < 8; ++j) V[bb][j] = 0.f;
        #pragma unroll
        for (int k = 0; k < K_; ++k) {
            float w[8];
            #pragma unroll
            for (int j = 0; j < 8; ++j) w[j] = sW[k * O_ + j * 64 + lane];
            #pragma unroll
            for (int bb = 0; bb < 4; ++bb) {
                const float xb = sX[(wave * 4 + bb) * K_ + k];
                #pragma unroll
                for (int j = 0; j < 8; ++j) V[bb][j] = fmaf(xb, w[j], V[bb][j]);
            }
        }

        #pragma unroll
        for (int bb = 0; bb < 4; ++bb) {
            if (PASS == 0) {
                #pragma unroll
                for (int j = 0; j < 8; ++j) facc[bb][j] += V[bb][j];
            } else {
                float p0 = 0.f;
                #pragma unroll
                for (int j = 0; j < 8; ++j) p0 = fmaf(V[bb][j], a0[bb][j], p0);
                p0 += __shfl_xor(p0, 32);       // combine the two a-halves
                float lg = p0;
                if (PASS == 2) {
                    float p1 = 0.f;
                    #pragma unroll
                    for (int j = 0; j < 8; ++j) p1 = fmaf(V[bb][j], a1[bb][j], p1);
                    p1 += __shfl_xor(p1, 32);
                    lg += p1;
                }
                // softmax over the 32 d's (lanes 0..31, duplicated 32..63)
                float mx = lg;
                mx = fmaxf(mx, __shfl_xor(mx, 1));
                mx = fmaxf(mx, __shfl_xor(mx, 2));
                mx = fmaxf(mx, __shfl_xor(mx, 4));
                mx = fmaxf(mx, __shfl_xor(mx, 8));
                mx = fmaxf(mx, __shfl_xor(mx, 16));
                const float e = __expf(lg - mx);
                float s = e;
                s += __shfl_xor(s, 1);
                s += __shfl_xor(s, 2);
                s += __shfl_xor(s, 4);
                s += __shfl_xor(s, 8);
                s += __shfl_xor(s, 16);
                const float r = e * __builtin_amdgcn_rcpf(s);
                #pragma unroll
                for (int j = 0; j < 8; ++j)
                    facc[bb][j] = fmaf(r, V[bb][j], facc[bb][j]);
            }
        }
    }

    // flush per-(ig) partials; rows disjoint across bh
    #pragma unroll
    for (int bb = 0; bb < 4; ++bb) {
        const int b = bh * 16 + wave * 4 + bb;
        float4* dst = (float4*)(partial + ((size_t)ig * B_ + b) * O_ + obase);
        dst[0] = make_float4(facc[bb][0], facc[bb][1], facc[bb][2], facc[bb][3]);
        dst[1] = make_float4(facc[bb][4], facc[bb][5], facc[bb][6], facc[bb][7]);
    }
}

// sum NG_ partials -> *scale + bias -> squash over A -> out
// 256 wgs x 256 thr; wg covers 64 g's; 4 w-slices of 64 reduced via LDS.
__global__ __launch_bounds__(256)
void reduce_squash(const float* __restrict__ partial, const float* __restrict__ bias,
                   float scale, float* __restrict__ out)
{
    const int t  = threadIdx.x;
    const int g  = blockIdx.x * 64 + (t & 63);   // b*512 + o
    const int ws = t >> 6;                       // w-slice 0..3
    float s = 0.f;
    #pragma unroll 8
    for (int w = ws * 64; w < ws * 64 + 64; ++w)
        s += partial[(size_t)w * (B_ * O_) + g];
    __shared__ float red[256];
    red[t] = s;
    __syncthreads();
    if (t < 64) {
        s = red[t] + red[t + 64] + red[t + 128] + red[t + 192];
        const float p = fmaf(s, scale, bias[g & (O_ - 1)]);
        float nn = p * p;
        nn += __shfl_xor(nn, 1);
        nn += __shfl_xor(nn, 2);
        nn += __shfl_xor(nn, 4);
        nn += __shfl_xor(nn, 8);
        out[g] = p * sqrtf(nn) / (1.f + nn);
    }
}

extern "C" void kernel_launch(void* const* d_in, const int* in_sizes, int n_in,
                              void* d_out, int out_size, void* d_ws, size_t ws_size,
                              hipStream_t stream) {
    const float* x    = (const float*)d_in[0];   // [32,2048,16]
    const float* W    = (const float*)d_in[1];   // [2048,16,512]
    const float* bias = (const float*)d_in[2];   // [512]
    float* out = (float*)d_out;                  // [32,512]

    float* partial = (float*)d_ws;                       // NG_*32*512 f32 = 16.8 MB
    float* act0    = partial + (size_t)NG_ * B_ * O_;    // 64 KB
    float* act1    = act0 + B_ * O_;                     // 64 KB

    sweep_kernel<0><<<NG_ * 2, 256, 0, stream>>>(x, W, nullptr, nullptr, partial);
    reduce_squash<<<256, 256, 0, stream>>>(partial, bias, 1.f / 32.f, act0);
    sweep_kernel<1><<<NG_ * 2, 256, 0, stream>>>(x, W, act0, nullptr, partial);
    reduce_squash<<<256, 256, 0, stream>>>(partial, bias, 1.f, act1);
    sweep_kernel<2><<<NG_ * 2, 256, 0, stream>>>(x, W, act0, act1, partial);
    reduce_squash<<<256, 256, 0, stream>>>(partial, bias, 1.f, out);
}

// Round 3
// 188.429 us; speedup vs baseline: 1.5044x; 1.1965x over previous
//
#include <hip/hip_runtime.h>

// CapsuleLayer dynamic routing, MI355X. R3: b128 LDS layout + scalar x loads.
// B=32, I=2048, K=16, O=D*A=512 (D=32, A=16), num_routing=3.
//
// Lane layout (sweep): lane l owns d = l>>1, h = l&1, outputs
// o = d*16 + h*8 + j (j=0..7).
//   - a-half combine: shfl_xor(.,1)  (quad-perm DPP, VALU pipe)
//   - softmax over D: shfl_xor {2,4,8,16,32}
// LDS W layout: sW[(j>>2)*4096 + k*256 + (d*2+h)*4 + (j&3)] so
//   - hot-loop read = 2x ds_read_b128 per k at lane-contiguous lane*4
//   - staging store = 1x ds_write_b128 per loaded global float4
// both with minimal (8 words/bank) distribution -> no conflicts.
// x is loaded via wave-uniform (SGPR) scalar loads -- no LDS broadcasts.

#define B_  32
#define I_  2048
#define K_  16
#define O_  512
#define NG_ 256   // i-groups (partial-buffer leading dim)
#define IC_ 8     // i's per group

template<int PASS>
__global__ __launch_bounds__(256)
void sweep_kernel(const float* __restrict__ x, const float* __restrict__ W,
                  const float* __restrict__ act0_g, const float* __restrict__ act1_g,
                  float* __restrict__ partial)
{
    const int tid  = threadIdx.x;
    const int lane = tid & 63;
    const int wave = tid >> 6;              // 0..3
    const int ig   = blockIdx.x >> 1;       // i-group
    const int bh   = blockIdx.x & 1;        // batch half
    const int d    = lane >> 1;             // 0..31
    const int h    = lane & 1;
    const int obase = d * 16 + h * 8;       // lane's first o

    // wave-uniform batch base (forces SGPR so x loads go scalar)
    const int wv   = __builtin_amdgcn_readfirstlane(wave);
    const int bbase = bh * 16 + wv * 4;

    __shared__ float sW[K_ * O_];           // 32 KB, permuted W[i] tile

    float facc[4][8];
    #pragma unroll
    for (int bb = 0; bb < 4; ++bb)
        #pragma unroll
        for (int j = 0; j < 8; ++j) facc[bb][j] = 0.f;

    float a0[4][8], a1[4][8];
    if (PASS >= 1) {
        #pragma unroll
        for (int bb = 0; bb < 4; ++bb) {
            const float4* p = (const float4*)(act0_g + (bbase + bb) * O_ + obase);
            float4 f0 = p[0], f1 = p[1];
            a0[bb][0]=f0.x; a0[bb][1]=f0.y; a0[bb][2]=f0.z; a0[bb][3]=f0.w;
            a0[bb][4]=f1.x; a0[bb][5]=f1.y; a0[bb][6]=f1.z; a0[bb][7]=f1.w;
        }
    }
    if (PASS == 2) {
        #pragma unroll
        for (int bb = 0; bb < 4; ++bb) {
            const float4* p = (const float4*)(act1_g + (bbase + bb) * O_ + obase);
            float4 f0 = p[0], f1 = p[1];
            a1[bb][0]=f0.x; a1[bb][1]=f0.y; a1[bb][2]=f0.z; a1[bb][3]=f0.w;
            a1[bb][4]=f1.x; a1[bb][5]=f1.y; a1[bb][6]=f1.z; a1[bb][7]=f1.w;
        }
    }

    for (int ii = 0; ii < IC_; ++ii) {
        const int i = ig * IC_ + ii;
        __syncthreads();   // protect prior iteration's LDS reads
        // stage W[i] permuted: 2048 float4s, 8 per thread, 1 ds_write_b128 each
        {
            const float4* Wg = (const float4*)(W + (size_t)i * (K_ * O_));
            #pragma unroll
            for (int q = 0; q < 8; ++q) {
                const int f  = tid + 256 * q;
                float4 w4 = Wg[f];
                const int e0 = 4 * f;
                const int k  = e0 >> 9;
                const int o  = e0 & (O_ - 1);
                const int dd = o >> 4;
                const int aa = o & 15;
                const int hh = aa >> 3;
                const int jq = (aa >> 2) & 1;
                *(float4*)&sW[jq * 4096 + k * 256 + (dd * 2 + hh) * 4] = w4;
            }
        }
        // x for this wave's 4 b's: wave-uniform scalar loads (SGPRs)
        float xs[4][16];
        #pragma unroll
        for (int bb = 0; bb < 4; ++bb) {
            const float4* xp = (const float4*)(x + ((size_t)(bbase + bb) * I_ + i) * K_);
            #pragma unroll
            for (int q = 0; q < 4; ++q) {
                float4 v = xp[q];
                xs[bb][4*q+0]=v.x; xs[bb][4*q+1]=v.y; xs[bb][4*q+2]=v.z; xs[bb][4*q+3]=v.w;
            }
        }
        __syncthreads();

        // V[bb][j]: 2 ds_read_b128 per k
        float V[4][8];
        #pragma unroll
        for (int bb = 0; bb < 4; ++bb)
            #pragma unroll
            for (int j = 0; j < 8; ++j) V[bb][j] = 0.f;
        #pragma unroll
        for (int k = 0; k < K_; ++k) {
            const float4 w0 = *(const float4*)&sW[k * 256 + lane * 4];
            const float4 w1 = *(const float4*)&sW[4096 + k * 256 + lane * 4];
            const float w[8] = {w0.x, w0.y, w0.z, w0.w, w1.x, w1.y, w1.z, w1.w};
            #pragma unroll
            for (int bb = 0; bb < 4; ++bb) {
                const float xb = xs[bb][k];
                #pragma unroll
                for (int j = 0; j < 8; ++j) V[bb][j] = fmaf(xb, w[j], V[bb][j]);
            }
        }

        #pragma unroll
        for (int bb = 0; bb < 4; ++bb) {
            if (PASS == 0) {
                #pragma unroll
                for (int j = 0; j < 8; ++j) facc[bb][j] += V[bb][j];
            } else {
                float p0 = 0.f;
                #pragma unroll
                for (int j = 0; j < 8; ++j) p0 = fmaf(V[bb][j], a0[bb][j], p0);
                p0 += __shfl_xor(p0, 1);        // combine the two a-halves
                float lg = p0;
                if (PASS == 2) {
                    float p1 = 0.f;
                    #pragma unroll
                    for (int j = 0; j < 8; ++j) p1 = fmaf(V[bb][j], a1[bb][j], p1);
                    p1 += __shfl_xor(p1, 1);
                    lg += p1;
                }
                // softmax over 32 d's (no max-sub: |logits| small, f32-safe)
                const float e = __expf(lg);
                float s = e;
                s += __shfl_xor(s, 2);
                s += __shfl_xor(s, 4);
                s += __shfl_xor(s, 8);
                s += __shfl_xor(s, 16);
                s += __shfl_xor(s, 32);
                const float r = e * __builtin_amdgcn_rcpf(s);
                #pragma unroll
                for (int j = 0; j < 8; ++j)
                    facc[bb][j] = fmaf(r, V[bb][j], facc[bb][j]);
            }
        }
    }

    // flush per-(ig) partials
    #pragma unroll
    for (int bb = 0; bb < 4; ++bb) {
        const int b = bbase + bb;
        float4* dst = (float4*)(partial + ((size_t)ig * B_ + b) * O_ + obase);
        dst[0] = make_float4(facc[bb][0], facc[bb][1], facc[bb][2], facc[bb][3]);
        dst[1] = make_float4(facc[bb][4], facc[bb][5], facc[bb][6], facc[bb][7]);
    }
}

// sum NG_ partials -> *scale + bias -> squash over A -> out
// 512 wgs x 256 thr; wg covers 32 g's; 8 w-slices of 32 reduced via LDS.
__global__ __launch_bounds__(256)
void reduce_squash(const float* __restrict__ partial, const float* __restrict__ bias,
                   float scale, float* __restrict__ out)
{
    const int t  = threadIdx.x;
    const int g  = blockIdx.x * 32 + (t & 31);   // b*512 + o
    const int sl = t >> 5;                       // w-slice 0..7
    float s = 0.f;
    #pragma unroll
    for (int w = sl * 32; w < sl * 32 + 32; ++w)
        s += partial[(size_t)w * (B_ * O_) + g];
    __shared__ float red[256];
    red[t] = s;
    __syncthreads();
    if (t < 32) {
        float v = red[t];
        #pragma unroll
        for (int r = 1; r < 8; ++r) v += red[t + 32 * r];
        const float p = fmaf(v, scale, bias[g & (O_ - 1)]);
        float nn = p * p;
        nn += __shfl_xor(nn, 1);
        nn += __shfl_xor(nn, 2);
        nn += __shfl_xor(nn, 4);
        nn += __shfl_xor(nn, 8);
        out[g] = p * sqrtf(nn) / (1.f + nn);
    }
}

extern "C" void kernel_launch(void* const* d_in, const int* in_sizes, int n_in,
                              void* d_out, int out_size, void* d_ws, size_t ws_size,
                              hipStream_t stream) {
    const float* x    = (const float*)d_in[0];   // [32,2048,16]
    const float* W    = (const float*)d_in[1];   // [2048,16,512]
    const float* bias = (const float*)d_in[2];   // [512]
    float* out = (float*)d_out;                  // [32,512]

    float* partial = (float*)d_ws;                       // NG_*32*512 f32 = 16.8 MB
    float* act0    = partial + (size_t)NG_ * B_ * O_;    // 64 KB
    float* act1    = act0 + B_ * O_;                     // 64 KB

    sweep_kernel<0><<<NG_ * 2, 256, 0, stream>>>(x, W, nullptr, nullptr, partial);
    reduce_squash<<<512, 256, 0, stream>>>(partial, bias, 1.f / 32.f, act0);
    sweep_kernel<1><<<NG_ * 2, 256, 0, stream>>>(x, W, act0, nullptr, partial);
    reduce_squash<<<512, 256, 0, stream>>>(partial, bias, 1.f, act1);
    sweep_kernel<2><<<NG_ * 2, 256, 0, stream>>>(x, W, act0, act1, partial);
    reduce_squash<<<512, 256, 0, stream>>>(partial, bias, 1.f, out);
}